// Round 4
// baseline (478.481 us; speedup 1.0000x reference)
//
#include <hip/hip_runtime.h>
#include <cstdint>
#include <cstddef>

#define NN 50000
#define EE 800000
#define DD 128
#define NBLK 196    // ceil(NN/256)
#define RS 132      // LDS row stride (floats), padded: breaks stride-512B bank conflicts

// ---------------- ws layout (bytes) ----------------
// deg      [N] int      @ 0        (200000)  -- count target; zeroed by scatter_scan; reused as fill cursor
// bsum     [NBLK] int   @ 200000   (784)
// boff     [NBLK+1] int @ 200832   (788)
// row_ptr  [N+1] int    @ 400000   (200004)
// csr_src  [E] int      @ 600064   (3200000)
// dinv     [N] float    @ 3800064  (200000)
// flag     [1] int      @ 4000064  (4)
// H        [N*D] bf16   @ 4000256  (12800000)
// total: 16,800,256 bytes

__device__ __forceinline__ void fma4(float4& a, float s, const float4& v) {
    a.x = fmaf(s, v.x, a.x);
    a.y = fmaf(s, v.y, a.y);
    a.z = fmaf(s, v.z, a.z);
    a.w = fmaf(s, v.w, a.w);
}

// fp32 -> bf16 (RNE) and bf16-pair unpack
__device__ __forceinline__ unsigned int f2bf(float f) {
    unsigned int u = __float_as_uint(f);
    u += 0x7fffu + ((u >> 16) & 1u);
    return u >> 16;
}
__device__ __forceinline__ float bflo(unsigned int u) { return __uint_as_float(u << 16); }
__device__ __forceinline__ float bfhi(unsigned int u) { return __uint_as_float(u & 0xffff0000u); }

__device__ __forceinline__ int ld_idx(const int* __restrict__ p, long long i, int mode64) {
    // mode64: data is int64 little-endian, value fits in low dword
    return mode64 ? p[2 * i] : p[(size_t)i];
}

// Detect whether edge_index arrived as int64 (high dwords all zero) or int32.
__global__ void probe_kernel(const int* __restrict__ ei, int* __restrict__ flag) {
    int t = threadIdx.x;
    int v = ei[2 * t + 1];                 // odd dwords of first 64 qwords
    unsigned long long b = __ballot(v != 0);
    if (t == 0) *flag = (b == 0ull) ? 1 : 0;
}

__global__ void count_kernel(const int* __restrict__ ei, const int* __restrict__ flag,
                             int* __restrict__ deg) {
    int e = blockIdx.x * 256 + threadIdx.x;
    if (e >= EE) return;
    int m = *flag;
    int d = ld_idx(ei, (long long)EE + e, m);
    atomicAdd(&deg[d], 1);
}

// ---- decoupled scan: per-block sums -> scan of sums -> per-chunk scan ----
__global__ __launch_bounds__(256) void partial_kernel(const int* __restrict__ deg,
                                                      int* __restrict__ bsum) {
    int idx = blockIdx.x * 256 + threadIdx.x;
    int v = (idx < NN) ? deg[idx] : 0;
    for (int off = 1; off < 64; off <<= 1) v += __shfl_xor(v, off);
    __shared__ int ws[4];
    if ((threadIdx.x & 63) == 0) ws[threadIdx.x >> 6] = v;
    __syncthreads();
    if (threadIdx.x == 0) bsum[blockIdx.x] = ws[0] + ws[1] + ws[2] + ws[3];
}

__global__ __launch_bounds__(256) void bscan_kernel(const int* __restrict__ bsum,
                                                    int* __restrict__ boff) {
    __shared__ int sh[256];
    int t = threadIdx.x;
    sh[t] = (t < NBLK) ? bsum[t] : 0;
    __syncthreads();
    for (int off = 1; off < 256; off <<= 1) {
        int u = (t >= off) ? sh[t - off] : 0;
        __syncthreads();
        sh[t] += u;
        __syncthreads();
    }
    if (t <= NBLK) boff[t] = (t == 0) ? 0 : sh[t - 1];   // exclusive; boff[NBLK] = total
}

__global__ __launch_bounds__(256) void scatter_scan_kernel(
        int* __restrict__ deg, const int* __restrict__ boff,
        int* __restrict__ row_ptr, float* __restrict__ dinv) {
    __shared__ int sh[256];
    int t = threadIdx.x;
    int idx = blockIdx.x * 256 + t;
    int v = (idx < NN) ? deg[idx] : 0;
    sh[t] = v;
    __syncthreads();
    for (int off = 1; off < 256; off <<= 1) {
        int u = (t >= off) ? sh[t - off] : 0;
        __syncthreads();
        sh[t] += u;
        __syncthreads();
    }
    if (idx < NN) {
        row_ptr[idx] = boff[blockIdx.x] + sh[t] - v;   // exclusive prefix
        dinv[idx] = rsqrtf((float)(v + 1));            // +1 = self loop; always > 0
        deg[idx] = 0;                                  // becomes fill's cursor
    }
    if (idx == 0) row_ptr[NN] = boff[NBLK];
}

__global__ void fill_kernel(const int* __restrict__ ei, const int* __restrict__ flag,
                            const int* __restrict__ row_ptr, int* __restrict__ cursor,
                            int* __restrict__ csr_src) {
    int e = blockIdx.x * 256 + threadIdx.x;
    if (e >= EE) return;
    int m = *flag;
    int sv = ld_idx(ei, (long long)e, m);
    int dv = ld_idx(ei, (long long)EE + e, m);
    int pos = row_ptr[dv] + atomicAdd(&cursor[dv], 1);
    csr_src[pos] = sv;
}

// H(bf16) = rmsnorm(X, g) @ W.  Block: 256 thr, 64 rows.  xn in LDS (33KB, padded).
// Stage: thread t -> row t>>2, 32 floats at (t&3)*32.
// GEMM:  thread (tc=t&31, tr=t>>5) -> rows tr*8..tr*8+7, cols 4*tc..4*tc+3.
__global__ __launch_bounds__(256) void rmsnorm_gemm_kernel(
        const float* __restrict__ X, const float* __restrict__ W,
        const float* __restrict__ g, unsigned int* __restrict__ H) {
    __shared__ float xn[64 * RS];
    int t = threadIdx.x;
    int row0 = blockIdx.x * 64;

    // ---- stage + rmsnorm
    int r = t >> 2, part = t & 3;
    int row = row0 + r;
    float4 v[8];
    float ss = 0.f;
    if (row < NN) {
        const float4* xr = (const float4*)(X + (size_t)row * DD) + part * 8;
        #pragma unroll
        for (int i = 0; i < 8; i++) {
            v[i] = xr[i];
            ss += v[i].x * v[i].x + v[i].y * v[i].y + v[i].z * v[i].z + v[i].w * v[i].w;
        }
    } else {
        #pragma unroll
        for (int i = 0; i < 8; i++) v[i] = make_float4(0.f, 0.f, 0.f, 0.f);
    }
    // 4 lanes per row, consecutive -> xor reduce
    ss += __shfl_xor(ss, 1);
    ss += __shfl_xor(ss, 2);
    float sc = rsqrtf(ss * (1.0f / DD) + 1e-6f);

    const float4* g4 = (const float4*)g + part * 8;
    float4* xrow = (float4*)(&xn[r * RS]) + part * 8;
    #pragma unroll
    for (int i = 0; i < 8; i++) {
        float4 gq = g4[i], q;
        q.x = v[i].x * sc * gq.x;
        q.y = v[i].y * sc * gq.y;
        q.z = v[i].z * sc * gq.z;
        q.w = v[i].w * sc * gq.w;
        xrow[i] = q;
    }
    __syncthreads();

    // ---- gemm: W read from global (64KB, L2-resident), 8 rows x 4 cols per thread
    int tc = t & 31, tr = t >> 5;
    int r0 = tr * 8;
    const float4* W4 = (const float4*)W;   // [k][32] float4
    float4 acc[8];
    #pragma unroll
    for (int i = 0; i < 8; i++) acc[i] = make_float4(0.f, 0.f, 0.f, 0.f);
    #pragma unroll 2
    for (int k = 0; k < DD; k += 4) {
        float4 w0 = W4[(k + 0) * 32 + tc];
        float4 w1 = W4[(k + 1) * 32 + tc];
        float4 w2 = W4[(k + 2) * 32 + tc];
        float4 w3 = W4[(k + 3) * 32 + tc];
        #pragma unroll
        for (int i = 0; i < 8; i++) {
            float4 xv = *(const float4*)&xn[(r0 + i) * RS + k];
            fma4(acc[i], xv.x, w0);
            fma4(acc[i], xv.y, w1);
            fma4(acc[i], xv.z, w2);
            fma4(acc[i], xv.w, w3);
        }
    }
    #pragma unroll
    for (int i = 0; i < 8; i++) {
        int rb = row0 + r0 + i;
        if (rb < NN) {
            uint2 o;
            o.x = f2bf(acc[i].x) | (f2bf(acc[i].y) << 16);
            o.y = f2bf(acc[i].z) | (f2bf(acc[i].w) << 16);
            ((uint2*)(H + (size_t)rb * 64))[tc] = o;   // H row = 64 uints = 256B
        }
    }
}

// out[n] = relu( sum_{e:dst=n} H[src]*dinv[src]*dinv[n] + H[n]*dinv[n]^2 + b )
// One wave per node; halves of the wave take alternate edges; 32 lanes x 4 bf16 (8B).
__global__ __launch_bounds__(256) void aggregate_kernel(
        const unsigned int* __restrict__ Hm, const float* __restrict__ dinv,
        const int* __restrict__ row_ptr, const int* __restrict__ csr_src,
        const float* __restrict__ b, float* __restrict__ out) {
    int wv = threadIdx.x >> 6;
    int lane = threadIdx.x & 63;
    int n = blockIdx.x * 4 + wv;          // grid = N/4 exactly
    int half = lane >> 5;
    int tc = lane & 31;
    const uint2* H2 = (const uint2*)Hm;   // row = 32 uint2 = 256B
    float dn = dinv[n];
    float4 acc = {0.f, 0.f, 0.f, 0.f};
    if (half == 0) {                      // self loop + bias, added once
        uint2 q = H2[(size_t)n * 32 + tc];
        float4 bv = ((const float4*)b)[tc];
        float w = dn * dn;
        acc.x = fmaf(bflo(q.x), w, bv.x);
        acc.y = fmaf(bfhi(q.x), w, bv.y);
        acc.z = fmaf(bflo(q.y), w, bv.z);
        acc.w = fmaf(bfhi(q.y), w, bv.w);
    }
    int start = row_ptr[n], end = row_ptr[n + 1];
    for (int e = start + half; e < end; e += 2) {
        int s = csr_src[e];
        float w = dinv[s] * dn;
        uint2 q = H2[(size_t)s * 32 + tc];
        acc.x = fmaf(bflo(q.x), w, acc.x);
        acc.y = fmaf(bfhi(q.x), w, acc.y);
        acc.z = fmaf(bflo(q.y), w, acc.z);
        acc.w = fmaf(bfhi(q.y), w, acc.w);
    }
    acc.x += __shfl_xor(acc.x, 32);
    acc.y += __shfl_xor(acc.y, 32);
    acc.z += __shfl_xor(acc.z, 32);
    acc.w += __shfl_xor(acc.w, 32);
    if (half == 0) {
        acc.x = fmaxf(acc.x, 0.f);
        acc.y = fmaxf(acc.y, 0.f);
        acc.z = fmaxf(acc.z, 0.f);
        acc.w = fmaxf(acc.w, 0.f);
        ((float4*)(out + (size_t)n * DD))[tc] = acc;
    }
}

extern "C" void kernel_launch(void* const* d_in, const int* in_sizes, int n_in,
                              void* d_out, int out_size, void* d_ws, size_t ws_size,
                              hipStream_t stream) {
    (void)in_sizes; (void)n_in; (void)out_size; (void)ws_size;
    const float* x  = (const float*)d_in[0];
    const int*   ei = (const int*)d_in[1];
    const float* W1 = (const float*)d_in[2];
    const float* b1 = (const float*)d_in[3];
    const float* g1 = (const float*)d_in[4];
    const float* W2 = (const float*)d_in[5];
    const float* b2 = (const float*)d_in[6];
    const float* g2 = (const float*)d_in[7];
    const float* W3 = (const float*)d_in[8];
    const float* b3 = (const float*)d_in[9];
    const float* g3 = (const float*)d_in[10];
    float* out = (float*)d_out;

    char* wsb = (char*)d_ws;
    int*   deg     = (int*)(wsb + 0);        // doubles as fill cursor
    int*   bsum    = (int*)(wsb + 200000);
    int*   boff    = (int*)(wsb + 200832);
    int*   row_ptr = (int*)(wsb + 400000);
    int*   csr_src = (int*)(wsb + 600064);
    float* dinv    = (float*)(wsb + 3800064);
    int*   flag    = (int*)(wsb + 4000064);
    unsigned int* Hb = (unsigned int*)(wsb + 4000256);   // bf16 pairs

    hipMemsetAsync(deg, 0, 200000, stream);

    probe_kernel<<<1, 64, 0, stream>>>(ei, flag);
    count_kernel<<<(EE + 255) / 256, 256, 0, stream>>>(ei, flag, deg);
    partial_kernel<<<NBLK, 256, 0, stream>>>(deg, bsum);
    bscan_kernel<<<1, 256, 0, stream>>>(bsum, boff);
    scatter_scan_kernel<<<NBLK, 256, 0, stream>>>(deg, boff, row_ptr, dinv);
    fill_kernel<<<(EE + 255) / 256, 256, 0, stream>>>(ei, flag, row_ptr, deg, csr_src);

    const int gemm_grid = (NN + 63) / 64;   // 782
    const int agg_grid  = NN / 4;           // 12500

    // layer 1: x -> H -> out (out doubles as ping buffer)
    rmsnorm_gemm_kernel<<<gemm_grid, 256, 0, stream>>>(x, W1, g1, Hb);
    aggregate_kernel<<<agg_grid, 256, 0, stream>>>(Hb, dinv, row_ptr, csr_src, b1, out);
    // layer 2: out -> H -> out
    rmsnorm_gemm_kernel<<<gemm_grid, 256, 0, stream>>>(out, W2, g2, Hb);
    aggregate_kernel<<<agg_grid, 256, 0, stream>>>(Hb, dinv, row_ptr, csr_src, b2, out);
    // layer 3: out -> H -> d_out
    rmsnorm_gemm_kernel<<<gemm_grid, 256, 0, stream>>>(out, W3, g3, Hb);
    aggregate_kernel<<<agg_grid, 256, 0, stream>>>(Hb, dinv, row_ptr, csr_src, b3, out);
}

// Round 7
// 402.495 us; speedup vs baseline: 1.1888x; 1.1888x over previous
//
#include <hip/hip_runtime.h>
#include <cstdint>
#include <cstddef>

#define NN 50000
#define EE 800000
#define DD 128
#define NBLK 196    // ceil(NN/256)
#define RS 132      // LDS row stride (floats), padded

// ---------------- ws layout (bytes) ----------------
// deg      [N] int      @ 0        (200000)  -- zeroed by scatter_scan; reused as fill cursor
// bsum     [NBLK] int   @ 200000   (784)
// boff     [NBLK+1] int @ 200832   (788)
// row_ptr  [N+1] int    @ 400000   (200004)
// csr_src  [E] int      @ 600064   (3200000)
// dinv     [N] float    @ 3800064  (200000)
// flag     [1] int      @ 4000064  (4)
// H        [N*D] bf16   @ 4000256  (12800000)
// csr_w    [E] float    @ 16800256 (3200000)
// total: 20,000,256 bytes  (R2-R4 used 29.6MB, so ws_size is sufficient)

__device__ __forceinline__ void fma4(float4& a, float s, const float4& v) {
    a.x = fmaf(s, v.x, a.x);
    a.y = fmaf(s, v.y, a.y);
    a.z = fmaf(s, v.z, a.z);
    a.w = fmaf(s, v.w, a.w);
}

// fp32 -> bf16 (RNE) and bf16-pair unpack
__device__ __forceinline__ unsigned int f2bf(float f) {
    unsigned int u = __float_as_uint(f);
    u += 0x7fffu + ((u >> 16) & 1u);
    return u >> 16;
}
__device__ __forceinline__ float bflo(unsigned int u) { return __uint_as_float(u << 16); }
__device__ __forceinline__ float bfhi(unsigned int u) { return __uint_as_float(u & 0xffff0000u); }

__device__ __forceinline__ int ld_idx(const int* __restrict__ p, long long i, int mode64) {
    return mode64 ? p[2 * i] : p[(size_t)i];
}

// Detect whether edge_index arrived as int64 (high dwords all zero) or int32.
__global__ void probe_kernel(const int* __restrict__ ei, int* __restrict__ flag) {
    int t = threadIdx.x;
    int v = ei[2 * t + 1];
    unsigned long long b = __ballot(v != 0);
    if (t == 0) *flag = (b == 0ull) ? 1 : 0;
}

__global__ void count_kernel(const int* __restrict__ ei, const int* __restrict__ flag,
                             int* __restrict__ deg) {
    int e = blockIdx.x * 256 + threadIdx.x;
    if (e >= EE) return;
    int m = *flag;
    int d = ld_idx(ei, (long long)EE + e, m);
    atomicAdd(&deg[d], 1);
}

// ---- decoupled scan ----
__global__ __launch_bounds__(256) void partial_kernel(const int* __restrict__ deg,
                                                      int* __restrict__ bsum) {
    int idx = blockIdx.x * 256 + threadIdx.x;
    int v = (idx < NN) ? deg[idx] : 0;
    for (int off = 1; off < 64; off <<= 1) v += __shfl_xor(v, off);
    __shared__ int ws[4];
    if ((threadIdx.x & 63) == 0) ws[threadIdx.x >> 6] = v;
    __syncthreads();
    if (threadIdx.x == 0) bsum[blockIdx.x] = ws[0] + ws[1] + ws[2] + ws[3];
}

__global__ __launch_bounds__(256) void bscan_kernel(const int* __restrict__ bsum,
                                                    int* __restrict__ boff) {
    __shared__ int sh[256];
    int t = threadIdx.x;
    sh[t] = (t < NBLK) ? bsum[t] : 0;
    __syncthreads();
    for (int off = 1; off < 256; off <<= 1) {
        int u = (t >= off) ? sh[t - off] : 0;
        __syncthreads();
        sh[t] += u;
        __syncthreads();
    }
    if (t <= NBLK) boff[t] = (t == 0) ? 0 : sh[t - 1];
}

__global__ __launch_bounds__(256) void scatter_scan_kernel(
        int* __restrict__ deg, const int* __restrict__ boff,
        int* __restrict__ row_ptr, float* __restrict__ dinv) {
    __shared__ int sh[256];
    int t = threadIdx.x;
    int idx = blockIdx.x * 256 + t;
    int v = (idx < NN) ? deg[idx] : 0;
    sh[t] = v;
    __syncthreads();
    for (int off = 1; off < 256; off <<= 1) {
        int u = (t >= off) ? sh[t - off] : 0;
        __syncthreads();
        sh[t] += u;
        __syncthreads();
    }
    if (idx < NN) {
        row_ptr[idx] = boff[blockIdx.x] + sh[t] - v;
        dinv[idx] = rsqrtf((float)(v + 1));
        deg[idx] = 0;                                  // becomes fill's cursor
    }
    if (idx == 0) row_ptr[NN] = boff[NBLK];
}

__global__ void fill_kernel(const int* __restrict__ ei, const int* __restrict__ flag,
                            const int* __restrict__ row_ptr, int* __restrict__ cursor,
                            const float* __restrict__ dinv,
                            int* __restrict__ csr_src, float* __restrict__ csr_w) {
    int e = blockIdx.x * 256 + threadIdx.x;
    if (e >= EE) return;
    int m = *flag;
    int sv = ld_idx(ei, (long long)e, m);
    int dv = ld_idx(ei, (long long)EE + e, m);
    int pos = row_ptr[dv] + atomicAdd(&cursor[dv], 1);
    csr_src[pos] = sv;
    csr_w[pos] = dinv[sv];     // pre-gathered source weight
}

// H(bf16) = rmsnorm(X, g) @ W.  Block: 256 thr, 64 rows (unchanged from R4, passed).
__global__ __launch_bounds__(256) void rmsnorm_gemm_kernel(
        const float* __restrict__ X, const float* __restrict__ W,
        const float* __restrict__ g, unsigned int* __restrict__ H) {
    __shared__ float xn[64 * RS];
    int t = threadIdx.x;
    int row0 = blockIdx.x * 64;

    int r = t >> 2, part = t & 3;
    int row = row0 + r;
    float4 v[8];
    float ss = 0.f;
    if (row < NN) {
        const float4* xr = (const float4*)(X + (size_t)row * DD) + part * 8;
        #pragma unroll
        for (int i = 0; i < 8; i++) {
            v[i] = xr[i];
            ss += v[i].x * v[i].x + v[i].y * v[i].y + v[i].z * v[i].z + v[i].w * v[i].w;
        }
    } else {
        #pragma unroll
        for (int i = 0; i < 8; i++) v[i] = make_float4(0.f, 0.f, 0.f, 0.f);
    }
    ss += __shfl_xor(ss, 1);
    ss += __shfl_xor(ss, 2);
    float sc = rsqrtf(ss * (1.0f / DD) + 1e-6f);

    const float4* g4 = (const float4*)g + part * 8;
    float4* xrow = (float4*)(&xn[r * RS]) + part * 8;
    #pragma unroll
    for (int i = 0; i < 8; i++) {
        float4 gq = g4[i], q;
        q.x = v[i].x * sc * gq.x;
        q.y = v[i].y * sc * gq.y;
        q.z = v[i].z * sc * gq.z;
        q.w = v[i].w * sc * gq.w;
        xrow[i] = q;
    }
    __syncthreads();

    int tc = t & 31, tr = t >> 5;
    int r0 = tr * 8;
    const float4* W4 = (const float4*)W;
    float4 acc[8];
    #pragma unroll
    for (int i = 0; i < 8; i++) acc[i] = make_float4(0.f, 0.f, 0.f, 0.f);
    #pragma unroll 2
    for (int k = 0; k < DD; k += 4) {
        float4 w0 = W4[(k + 0) * 32 + tc];
        float4 w1 = W4[(k + 1) * 32 + tc];
        float4 w2 = W4[(k + 2) * 32 + tc];
        float4 w3 = W4[(k + 3) * 32 + tc];
        #pragma unroll
        for (int i = 0; i < 8; i++) {
            float4 xv = *(const float4*)&xn[(r0 + i) * RS + k];
            fma4(acc[i], xv.x, w0);
            fma4(acc[i], xv.y, w1);
            fma4(acc[i], xv.z, w2);
            fma4(acc[i], xv.w, w3);
        }
    }
    #pragma unroll
    for (int i = 0; i < 8; i++) {
        int rb = row0 + r0 + i;
        if (rb < NN) {
            uint2 o;
            o.x = f2bf(acc[i].x) | (f2bf(acc[i].y) << 16);
            o.y = f2bf(acc[i].z) | (f2bf(acc[i].w) << 16);
            ((uint2*)(H + (size_t)rb * 64))[tc] = o;
        }
    }
}

// out[n] = relu( sum_{e:dst=n} H[src]*csr_w[e]*dinv[n] + H[n]*dinv[n]^2 + b )
// One wave per node.  4 groups x 16 lanes; group reads a 256B bf16 row as uint4.
// Indices+weights staged per-wave in LDS (no cross-lane register ops in the
// edge path -> no shfl-under-divergence); H-row gathers stay independent.
__global__ __launch_bounds__(256) void aggregate_kernel(
        const unsigned int* __restrict__ Hm, const float* __restrict__ dinv,
        const int* __restrict__ row_ptr, const int* __restrict__ csr_src,
        const float* __restrict__ csr_w, const float* __restrict__ b,
        float* __restrict__ out) {
    __shared__ int   sIdx[4][64];
    __shared__ float sWt[4][64];
    int wv = threadIdx.x >> 6;
    int lane = threadIdx.x & 63;
    int n = blockIdx.x * 4 + wv;          // grid = N/4 exactly
    int grp = lane >> 4;
    int tc = lane & 15;
    const uint4* H4 = (const uint4*)Hm;   // row = 16 uint4 = 256B
    float dn = dinv[n];
    float acc[8];
    #pragma unroll
    for (int i = 0; i < 8; i++) acc[i] = 0.f;

    if (grp == 0) {                       // self loop + bias, added once
        uint4 q = H4[(size_t)n * 16 + tc];
        float w = dn * dn;
        const float4* b4 = (const float4*)b;
        float4 ba = b4[2 * tc], bb = b4[2 * tc + 1];
        acc[0] = fmaf(bflo(q.x), w, ba.x);
        acc[1] = fmaf(bfhi(q.x), w, ba.y);
        acc[2] = fmaf(bflo(q.y), w, ba.z);
        acc[3] = fmaf(bfhi(q.y), w, ba.w);
        acc[4] = fmaf(bflo(q.z), w, bb.x);
        acc[5] = fmaf(bfhi(q.z), w, bb.y);
        acc[6] = fmaf(bflo(q.w), w, bb.z);
        acc[7] = fmaf(bfhi(q.w), w, bb.w);
    }

    int start = row_ptr[n], end = row_ptr[n + 1];
    for (int base = start; base < end; base += 64) {
        int m = min(64, end - base);
        if (lane < m) {
            sIdx[wv][lane] = csr_src[base + lane];   // one coalesced load / 64 edges
            sWt[wv][lane]  = csr_w[base + lane];
        }
        // within-wave LDS write->read: DS ops issue in order; compiler inserts
        // lgkmcnt waits and cannot disprove aliasing, so no reorder.
        for (int j = grp; j < m; j += 4) {
            int s = sIdx[wv][j];
            float w = sWt[wv][j] * dn;
            uint4 q = H4[(size_t)s * 16 + tc];
            acc[0] = fmaf(bflo(q.x), w, acc[0]);
            acc[1] = fmaf(bfhi(q.x), w, acc[1]);
            acc[2] = fmaf(bflo(q.y), w, acc[2]);
            acc[3] = fmaf(bfhi(q.y), w, acc[3]);
            acc[4] = fmaf(bflo(q.z), w, acc[4]);
            acc[5] = fmaf(bfhi(q.z), w, acc[5]);
            acc[6] = fmaf(bflo(q.w), w, acc[6]);
            acc[7] = fmaf(bfhi(q.w), w, acc[7]);
        }
    }

    #pragma unroll
    for (int i = 0; i < 8; i++) {
        acc[i] += __shfl_xor(acc[i], 16);
        acc[i] += __shfl_xor(acc[i], 32);
    }
    if (grp == 0) {
        float4 o0, o1;
        o0.x = fmaxf(acc[0], 0.f); o0.y = fmaxf(acc[1], 0.f);
        o0.z = fmaxf(acc[2], 0.f); o0.w = fmaxf(acc[3], 0.f);
        o1.x = fmaxf(acc[4], 0.f); o1.y = fmaxf(acc[5], 0.f);
        o1.z = fmaxf(acc[6], 0.f); o1.w = fmaxf(acc[7], 0.f);
        float4* orow = (float4*)(out + (size_t)n * DD + 8 * tc);
        orow[0] = o0;
        orow[1] = o1;
    }
}

extern "C" void kernel_launch(void* const* d_in, const int* in_sizes, int n_in,
                              void* d_out, int out_size, void* d_ws, size_t ws_size,
                              hipStream_t stream) {
    (void)in_sizes; (void)n_in; (void)out_size; (void)ws_size;
    const float* x  = (const float*)d_in[0];
    const int*   ei = (const int*)d_in[1];
    const float* W1 = (const float*)d_in[2];
    const float* b1 = (const float*)d_in[3];
    const float* g1 = (const float*)d_in[4];
    const float* W2 = (const float*)d_in[5];
    const float* b2 = (const float*)d_in[6];
    const float* g2 = (const float*)d_in[7];
    const float* W3 = (const float*)d_in[8];
    const float* b3 = (const float*)d_in[9];
    const float* g3 = (const float*)d_in[10];
    float* out = (float*)d_out;

    char* wsb = (char*)d_ws;
    int*   deg     = (int*)(wsb + 0);        // doubles as fill cursor
    int*   bsum    = (int*)(wsb + 200000);
    int*   boff    = (int*)(wsb + 200832);
    int*   row_ptr = (int*)(wsb + 400000);
    int*   csr_src = (int*)(wsb + 600064);
    float* dinv    = (float*)(wsb + 3800064);
    int*   flag    = (int*)(wsb + 4000064);
    unsigned int* Hb = (unsigned int*)(wsb + 4000256);
    float* csr_w   = (float*)(wsb + 16800256);

    hipMemsetAsync(deg, 0, 200000, stream);

    probe_kernel<<<1, 64, 0, stream>>>(ei, flag);
    count_kernel<<<(EE + 255) / 256, 256, 0, stream>>>(ei, flag, deg);
    partial_kernel<<<NBLK, 256, 0, stream>>>(deg, bsum);
    bscan_kernel<<<1, 256, 0, stream>>>(bsum, boff);
    scatter_scan_kernel<<<NBLK, 256, 0, stream>>>(deg, boff, row_ptr, dinv);
    fill_kernel<<<(EE + 255) / 256, 256, 0, stream>>>(ei, flag, row_ptr, deg, dinv, csr_src, csr_w);

    const int gemm_grid = (NN + 63) / 64;   // 782
    const int agg_grid  = NN / 4;           // 12500

    rmsnorm_gemm_kernel<<<gemm_grid, 256, 0, stream>>>(x, W1, g1, Hb);
    aggregate_kernel<<<agg_grid, 256, 0, stream>>>(Hb, dinv, row_ptr, csr_src, csr_w, b1, out);
    rmsnorm_gemm_kernel<<<gemm_grid, 256, 0, stream>>>(out, W2, g2, Hb);
    aggregate_kernel<<<agg_grid, 256, 0, stream>>>(Hb, dinv, row_ptr, csr_src, csr_w, b2, out);
    rmsnorm_gemm_kernel<<<gemm_grid, 256, 0, stream>>>(out, W3, g3, Hb);
    aggregate_kernel<<<agg_grid, 256, 0, stream>>>(Hb, dinv, row_ptr, csr_src, csr_w, b3, out);
}

// Round 8
// 357.554 us; speedup vs baseline: 1.3382x; 1.1257x over previous
//
#include <hip/hip_runtime.h>
#include <cstdint>
#include <cstddef>

#define NN 50000
#define EE 800000
#define DD 128
#define NBLK 196    // ceil(NN/256)
#define RS 132      // LDS row stride (floats), padded

// ---------------- ws layout (bytes) ----------------
// deg      [N] int      @ 0        (200000)
// bsum     [NBLK] int   @ 200000   (784)
// boff     [NBLK+1] int @ 200832   (788)
// row_ptr  [N+1] int    @ 400000   (200004)
// rank     [E] int      @ 600064   (3200000)  -- edge's within-dst-row slot, from count's atomic
// dinv     [N] float    @ 3800064  (200000)
// flag     [1] int      @ 4000064  (4)
// H        [N*D] bf16   @ 4000256  (12800000)
// csr      [E] uint2    @ 16800256 (6400000)  -- packed (src, bitcast(dinv[src]))
// total: 23,200,256 bytes

__device__ __forceinline__ void fma4(float4& a, float s, const float4& v) {
    a.x = fmaf(s, v.x, a.x);
    a.y = fmaf(s, v.y, a.y);
    a.z = fmaf(s, v.z, a.z);
    a.w = fmaf(s, v.w, a.w);
}

// fp32 -> bf16 (RNE) and bf16-pair unpack
__device__ __forceinline__ unsigned int f2bf(float f) {
    unsigned int u = __float_as_uint(f);
    u += 0x7fffu + ((u >> 16) & 1u);
    return u >> 16;
}
__device__ __forceinline__ float bflo(unsigned int u) { return __uint_as_float(u << 16); }
__device__ __forceinline__ float bfhi(unsigned int u) { return __uint_as_float(u & 0xffff0000u); }

__device__ __forceinline__ int ld_idx(const int* __restrict__ p, long long i, int mode64) {
    return mode64 ? p[2 * i] : p[(size_t)i];
}

// Detect whether edge_index arrived as int64 (high dwords all zero) or int32.
__global__ void probe_kernel(const int* __restrict__ ei, int* __restrict__ flag) {
    int t = threadIdx.x;
    int v = ei[2 * t + 1];
    unsigned long long b = __ballot(v != 0);
    if (t == 0) *flag = (b == 0ull) ? 1 : 0;
}

// deg count; atomic return value doubles as the edge's within-row rank.
__global__ void count_kernel(const int* __restrict__ ei, const int* __restrict__ flag,
                             int* __restrict__ deg, int* __restrict__ rank) {
    int e = blockIdx.x * 256 + threadIdx.x;
    if (e >= EE) return;
    int m = *flag;
    int d = ld_idx(ei, (long long)EE + e, m);
    rank[e] = atomicAdd(&deg[d], 1);     // coalesced rank write
}

// ---- decoupled scan ----
__global__ __launch_bounds__(256) void partial_kernel(const int* __restrict__ deg,
                                                      int* __restrict__ bsum) {
    int idx = blockIdx.x * 256 + threadIdx.x;
    int v = (idx < NN) ? deg[idx] : 0;
    for (int off = 1; off < 64; off <<= 1) v += __shfl_xor(v, off);
    __shared__ int ws[4];
    if ((threadIdx.x & 63) == 0) ws[threadIdx.x >> 6] = v;
    __syncthreads();
    if (threadIdx.x == 0) bsum[blockIdx.x] = ws[0] + ws[1] + ws[2] + ws[3];
}

__global__ __launch_bounds__(256) void bscan_kernel(const int* __restrict__ bsum,
                                                    int* __restrict__ boff) {
    __shared__ int sh[256];
    int t = threadIdx.x;
    sh[t] = (t < NBLK) ? bsum[t] : 0;
    __syncthreads();
    for (int off = 1; off < 256; off <<= 1) {
        int u = (t >= off) ? sh[t - off] : 0;
        __syncthreads();
        sh[t] += u;
        __syncthreads();
    }
    if (t <= NBLK) boff[t] = (t == 0) ? 0 : sh[t - 1];
}

__global__ __launch_bounds__(256) void scatter_scan_kernel(
        const int* __restrict__ deg, const int* __restrict__ boff,
        int* __restrict__ row_ptr, float* __restrict__ dinv) {
    __shared__ int sh[256];
    int t = threadIdx.x;
    int idx = blockIdx.x * 256 + t;
    int v = (idx < NN) ? deg[idx] : 0;
    sh[t] = v;
    __syncthreads();
    for (int off = 1; off < 256; off <<= 1) {
        int u = (t >= off) ? sh[t - off] : 0;
        __syncthreads();
        sh[t] += u;
        __syncthreads();
    }
    if (idx < NN) {
        row_ptr[idx] = boff[blockIdx.x] + sh[t] - v;
        dinv[idx] = rsqrtf((float)(v + 1));
    }
    if (idx == 0) row_ptr[NN] = boff[NBLK];
}

// No atomic: pos = row_ptr[dst] + rank[e].  One packed 8B scattered store.
__global__ void fill_kernel(const int* __restrict__ ei, const int* __restrict__ flag,
                            const int* __restrict__ row_ptr, const int* __restrict__ rank,
                            const float* __restrict__ dinv, uint2* __restrict__ csr) {
    int e = blockIdx.x * 256 + threadIdx.x;
    if (e >= EE) return;
    int m = *flag;
    int sv = ld_idx(ei, (long long)e, m);
    int dv = ld_idx(ei, (long long)EE + e, m);
    int pos = row_ptr[dv] + rank[e];
    csr[pos] = make_uint2((unsigned)sv, __float_as_uint(dinv[sv]));
}

// H(bf16) = rmsnorm(X, g) @ W.  Block: 256 thr, 64 rows (unchanged, passed R4/R7).
__global__ __launch_bounds__(256) void rmsnorm_gemm_kernel(
        const float* __restrict__ X, const float* __restrict__ W,
        const float* __restrict__ g, unsigned int* __restrict__ H) {
    __shared__ float xn[64 * RS];
    int t = threadIdx.x;
    int row0 = blockIdx.x * 64;

    int r = t >> 2, part = t & 3;
    int row = row0 + r;
    float4 v[8];
    float ss = 0.f;
    if (row < NN) {
        const float4* xr = (const float4*)(X + (size_t)row * DD) + part * 8;
        #pragma unroll
        for (int i = 0; i < 8; i++) {
            v[i] = xr[i];
            ss += v[i].x * v[i].x + v[i].y * v[i].y + v[i].z * v[i].z + v[i].w * v[i].w;
        }
    } else {
        #pragma unroll
        for (int i = 0; i < 8; i++) v[i] = make_float4(0.f, 0.f, 0.f, 0.f);
    }
    ss += __shfl_xor(ss, 1);
    ss += __shfl_xor(ss, 2);
    float sc = rsqrtf(ss * (1.0f / DD) + 1e-6f);

    const float4* g4 = (const float4*)g + part * 8;
    float4* xrow = (float4*)(&xn[r * RS]) + part * 8;
    #pragma unroll
    for (int i = 0; i < 8; i++) {
        float4 gq = g4[i], q;
        q.x = v[i].x * sc * gq.x;
        q.y = v[i].y * sc * gq.y;
        q.z = v[i].z * sc * gq.z;
        q.w = v[i].w * sc * gq.w;
        xrow[i] = q;
    }
    __syncthreads();

    int tc = t & 31, tr = t >> 5;
    int r0 = tr * 8;
    const float4* W4 = (const float4*)W;
    float4 acc[8];
    #pragma unroll
    for (int i = 0; i < 8; i++) acc[i] = make_float4(0.f, 0.f, 0.f, 0.f);
    #pragma unroll 2
    for (int k = 0; k < DD; k += 4) {
        float4 w0 = W4[(k + 0) * 32 + tc];
        float4 w1 = W4[(k + 1) * 32 + tc];
        float4 w2 = W4[(k + 2) * 32 + tc];
        float4 w3 = W4[(k + 3) * 32 + tc];
        #pragma unroll
        for (int i = 0; i < 8; i++) {
            float4 xv = *(const float4*)&xn[(r0 + i) * RS + k];
            fma4(acc[i], xv.x, w0);
            fma4(acc[i], xv.y, w1);
            fma4(acc[i], xv.z, w2);
            fma4(acc[i], xv.w, w3);
        }
    }
    #pragma unroll
    for (int i = 0; i < 8; i++) {
        int rb = row0 + r0 + i;
        if (rb < NN) {
            uint2 o;
            o.x = f2bf(acc[i].x) | (f2bf(acc[i].y) << 16);
            o.y = f2bf(acc[i].z) | (f2bf(acc[i].w) << 16);
            ((uint2*)(H + (size_t)rb * 64))[tc] = o;
        }
    }
}

// out[n] = relu( sum_{e:dst=n} H[src]*w_e*dinv[n] + H[n]*dinv[n]^2 + b )
// One wave per node.  4 groups x 16 lanes; group reads a 256B bf16 row as uint4.
// Packed (src,w) entries staged per-wave in LDS; H-row gathers independent.
__global__ __launch_bounds__(256) void aggregate_kernel(
        const unsigned int* __restrict__ Hm, const float* __restrict__ dinv,
        const int* __restrict__ row_ptr, const uint2* __restrict__ csr,
        const float* __restrict__ b, float* __restrict__ out) {
    __shared__ uint2 sEdge[4][64];
    int wv = threadIdx.x >> 6;
    int lane = threadIdx.x & 63;
    int n = blockIdx.x * 4 + wv;          // grid = N/4 exactly
    int grp = lane >> 4;
    int tc = lane & 15;
    const uint4* H4 = (const uint4*)Hm;   // row = 16 uint4 = 256B
    float dn = dinv[n];
    float acc[8];
    #pragma unroll
    for (int i = 0; i < 8; i++) acc[i] = 0.f;

    if (grp == 0) {                       // self loop + bias, added once
        uint4 q = H4[(size_t)n * 16 + tc];
        float w = dn * dn;
        const float4* b4 = (const float4*)b;
        float4 ba = b4[2 * tc], bb = b4[2 * tc + 1];
        acc[0] = fmaf(bflo(q.x), w, ba.x);
        acc[1] = fmaf(bfhi(q.x), w, ba.y);
        acc[2] = fmaf(bflo(q.y), w, ba.z);
        acc[3] = fmaf(bfhi(q.y), w, ba.w);
        acc[4] = fmaf(bflo(q.z), w, bb.x);
        acc[5] = fmaf(bfhi(q.z), w, bb.y);
        acc[6] = fmaf(bflo(q.w), w, bb.z);
        acc[7] = fmaf(bfhi(q.w), w, bb.w);
    }

    int start = row_ptr[n], end = row_ptr[n + 1];
    for (int base = start; base < end; base += 64) {
        int m = min(64, end - base);
        if (lane < m) sEdge[wv][lane] = csr[base + lane];  // one coalesced 8B load / edge
        for (int j = grp; j < m; j += 4) {
            uint2 p = sEdge[wv][j];
            int s = (int)p.x;
            float w = __uint_as_float(p.y) * dn;
            uint4 q = H4[(size_t)s * 16 + tc];
            acc[0] = fmaf(bflo(q.x), w, acc[0]);
            acc[1] = fmaf(bfhi(q.x), w, acc[1]);
            acc[2] = fmaf(bflo(q.y), w, acc[2]);
            acc[3] = fmaf(bfhi(q.y), w, acc[3]);
            acc[4] = fmaf(bflo(q.z), w, acc[4]);
            acc[5] = fmaf(bfhi(q.z), w, acc[5]);
            acc[6] = fmaf(bflo(q.w), w, acc[6]);
            acc[7] = fmaf(bfhi(q.w), w, acc[7]);
        }
    }

    #pragma unroll
    for (int i = 0; i < 8; i++) {
        acc[i] += __shfl_xor(acc[i], 16);
        acc[i] += __shfl_xor(acc[i], 32);
    }
    if (grp == 0) {
        float4 o0, o1;
        o0.x = fmaxf(acc[0], 0.f); o0.y = fmaxf(acc[1], 0.f);
        o0.z = fmaxf(acc[2], 0.f); o0.w = fmaxf(acc[3], 0.f);
        o1.x = fmaxf(acc[4], 0.f); o1.y = fmaxf(acc[5], 0.f);
        o1.z = fmaxf(acc[6], 0.f); o1.w = fmaxf(acc[7], 0.f);
        float4* orow = (float4*)(out + (size_t)n * DD + 8 * tc);
        orow[0] = o0;
        orow[1] = o1;
    }
}

extern "C" void kernel_launch(void* const* d_in, const int* in_sizes, int n_in,
                              void* d_out, int out_size, void* d_ws, size_t ws_size,
                              hipStream_t stream) {
    (void)in_sizes; (void)n_in; (void)out_size; (void)ws_size;
    const float* x  = (const float*)d_in[0];
    const int*   ei = (const int*)d_in[1];
    const float* W1 = (const float*)d_in[2];
    const float* b1 = (const float*)d_in[3];
    const float* g1 = (const float*)d_in[4];
    const float* W2 = (const float*)d_in[5];
    const float* b2 = (const float*)d_in[6];
    const float* g2 = (const float*)d_in[7];
    const float* W3 = (const float*)d_in[8];
    const float* b3 = (const float*)d_in[9];
    const float* g3 = (const float*)d_in[10];
    float* out = (float*)d_out;

    char* wsb = (char*)d_ws;
    int*   deg     = (int*)(wsb + 0);
    int*   bsum    = (int*)(wsb + 200000);
    int*   boff    = (int*)(wsb + 200832);
    int*   row_ptr = (int*)(wsb + 400000);
    int*   rank    = (int*)(wsb + 600064);
    float* dinv    = (float*)(wsb + 3800064);
    int*   flag    = (int*)(wsb + 4000064);
    unsigned int* Hb = (unsigned int*)(wsb + 4000256);
    uint2* csr     = (uint2*)(wsb + 16800256);

    hipMemsetAsync(deg, 0, 200000, stream);

    probe_kernel<<<1, 64, 0, stream>>>(ei, flag);
    count_kernel<<<(EE + 255) / 256, 256, 0, stream>>>(ei, flag, deg, rank);
    partial_kernel<<<NBLK, 256, 0, stream>>>(deg, bsum);
    bscan_kernel<<<1, 256, 0, stream>>>(bsum, boff);
    scatter_scan_kernel<<<NBLK, 256, 0, stream>>>(deg, boff, row_ptr, dinv);
    fill_kernel<<<(EE + 255) / 256, 256, 0, stream>>>(ei, flag, row_ptr, rank, dinv, csr);

    const int gemm_grid = (NN + 63) / 64;   // 782
    const int agg_grid  = NN / 4;           // 12500

    rmsnorm_gemm_kernel<<<gemm_grid, 256, 0, stream>>>(x, W1, g1, Hb);
    aggregate_kernel<<<agg_grid, 256, 0, stream>>>(Hb, dinv, row_ptr, csr, b1, out);
    rmsnorm_gemm_kernel<<<gemm_grid, 256, 0, stream>>>(out, W2, g2, Hb);
    aggregate_kernel<<<agg_grid, 256, 0, stream>>>(Hb, dinv, row_ptr, csr, b2, out);
    rmsnorm_gemm_kernel<<<gemm_grid, 256, 0, stream>>>(out, W3, g3, Hb);
    aggregate_kernel<<<agg_grid, 256, 0, stream>>>(Hb, dinv, row_ptr, csr, b3, out);
}